// Round 7
// baseline (141.751 us; speedup 1.0000x reference)
//
#include <hip/hip_runtime.h>

#define NPTS 1024
#define DIM 64
#define KNN 16
#define NA 12
#define NCOL 192              // (a,k) rows, idx = a*16 + k

typedef __attribute__((ext_vector_type(8))) short bf16x8;
typedef __attribute__((ext_vector_type(4))) float f32x4;

static __device__ inline unsigned short f2bfu(float x) {
    __bf16 b = (__bf16)x;                       // hw v_cvt (RNE)
    return __builtin_bit_cast(unsigned short, b);
}
static __device__ inline bf16x8 load8_cvt(const float* p) {
    f32x4 u = *(const f32x4*)p;
    f32x4 v = *(const f32x4*)(p + 4);
    bf16x8 r;
    r[0] = (short)f2bfu(u[0]); r[1] = (short)f2bfu(u[1]); r[2] = (short)f2bfu(u[2]); r[3] = (short)f2bfu(u[3]);
    r[4] = (short)f2bfu(v[0]); r[5] = (short)f2bfu(v[1]); r[6] = (short)f2bfu(v[2]); r[7] = (short)f2bfu(v[3]);
    return r;
}

// T2-style XOR swizzle on a [192][64] u16 tile: xor the 16B-slot index (col bits 3-5)
// with row&7. Bijective per row; keeps 16B alignment for b128 frag reads; 16 c16-lanes
// land on 8 distinct slots (2-way = free, m136).
static __device__ inline int swz(int row, int col) {
    return (row << 6) + (col ^ ((row & 7) << 3));
}

// ---------------- prep kernel: 768 blocks x 256 thr (unchanged from round 6) ----------------
__global__ __launch_bounds__(256) void prep_kernel(const float* __restrict__ feats,
                                                   const float* __restrict__ to_qkv,
                                                   float* __restrict__ qkvT,
                                                   unsigned short* __restrict__ pack,
                                                   const float* __restrict__ pos2,
                                                   const float* __restrict__ am1,
                                                   const float* __restrict__ am2,
                                                   const float* __restrict__ xyz,
                                                   int* __restrict__ idxout) {
    __shared__ unsigned short XT[16][72];
    __shared__ float px[NPTS], py[NPTS], pz[NPTS];
    const int b = blockIdx.x;
    const int t = threadIdx.x;
    const int n0 = b * 16;
    const bool do_knn = (b < 256);

    if (b < 72 && t < 64) {
        int s = b;
        int c16p = t & 15, gp = t >> 4;
        const float* src;
        if (s < 8) {
            int nt = s >> 1, kt = s & 1;
            src = pos2 + (nt * 16 + c16p) * 64 + kt * 32 + gp * 8;
        } else if (s < 40) {
            int u = s - 8, hq = u >> 3, nt = (u >> 1) & 3, kt = u & 1;
            src = am1 + (hq * 64 + nt * 16 + c16p) * 64 + kt * 32 + gp * 8;
        } else {
            int u = s - 40, hq = u >> 3, nt = (u >> 1) & 3, kt = u & 1;
            src = am2 + (nt * 16 + c16p) * 256 + hq * 64 + kt * 32 + gp * 8;
        }
        unsigned short* dst = pack + (s * 64 + t) * 8;
        #pragma unroll
        for (int e = 0; e < 8; ++e) dst[e] = f2bfu(src[e]);
    }

    if (do_knn) {
        for (int m = t; m < NPTS; m += 256) {
            px[m] = xyz[m];
            py[m] = xyz[NPTS + m];
            pz[m] = xyz[2 * NPTS + m];
        }
    }
    for (int e = t; e < 16 * 64; e += 256) {
        int c = e & 15, i = e >> 4;
        XT[c][i] = f2bfu(feats[i * (NPTS * NA) + n0 + c]);
    }
    __syncthreads();

    const int lane = t & 63, w = t >> 6, c16 = lane & 15, g = lane >> 4;

    {
        const f32x4 zero4 = {0.f, 0.f, 0.f, 0.f};
        f32x4 acc[3] = {zero4, zero4, zero4};
        #pragma unroll
        for (int kt = 0; kt < 2; ++kt) {
            bf16x8 af = *(const bf16x8*)&XT[c16][kt * 32 + g * 8];
            #pragma unroll
            for (int ni = 0; ni < 3; ++ni) {
                int cd = (w * 3 + ni) * 16 + c16;
                bf16x8 bfr = load8_cvt(to_qkv + cd * 64 + kt * 32 + g * 8);
                acc[ni] = __builtin_amdgcn_mfma_f32_16x16x32_bf16(af, bfr, acc[ni], 0, 0, 0);
            }
        }
        #pragma unroll
        for (int ni = 0; ni < 3; ++ni) {
            int cd = (w * 3 + ni) * 16 + c16;
            int c = cd >> 6, d = cd & 63;
            #pragma unroll
            for (int r = 0; r < 4; ++r) {
                int na = n0 + 4 * g + r;
                qkvT[c * (NPTS * NA * DIM) + na * 64 + d] = acc[ni][r];
            }
        }
    }

    if (do_knn) {
        const int n = b * 4 + w;
        const float xn = px[n], yn = py[n], zn = pz[n];
        const float sqn = xn * xn + yn * yn + zn * zn;
        float dd[16]; int id[16];
        #pragma unroll
        for (int j = 0; j < 16; ++j) {
            int m = j * 64 + lane;
            float xm = px[m], ym = py[m], zm = pz[m];
            float sqm = xm * xm + ym * ym + zm * zm;
            float dot = xn * xm + yn * ym + zn * zm;
            dd[j] = sqn + sqm - 2.f * dot;
            id[j] = m;
        }
        for (int r = 0; r < KNN; ++r) {
            float bd = 1e30f; int bi = 0x7fffffff;
            #pragma unroll
            for (int j = 0; j < 16; ++j)
                if (dd[j] < bd || (dd[j] == bd && id[j] < bi)) { bd = dd[j]; bi = id[j]; }
            #pragma unroll
            for (int mask = 1; mask < 64; mask <<= 1) {
                float od = __shfl_xor(bd, mask);
                int oi = __shfl_xor(bi, mask);
                if (od < bd || (od == bd && oi < bi)) { bd = od; bi = oi; }
            }
            if (lane == 0) idxout[n * KNN + r] = bi;
            #pragma unroll
            for (int j = 0; j < 16; ++j)
                if (id[j] == bi) dd[j] = 1e30f;
        }
    }
}

// ---------------- attn kernel: round-4 structure + XOR-swizzled unpadded LDS (3 blocks/CU) ----------------
// 8 waves: mw = wave&3 -> m-tiles {mw, mw+4, mw+8}; nw = wave>>2 -> n-tiles {2nw, 2nw+1}.
// C layout: lane(c16,g) reg r holds D[(a=mt, k=4g+r)][out = nt*16+c16].
__global__ __launch_bounds__(512, 6) void attn_main(const float* __restrict__ xyz,
                                                    const float* __restrict__ anchors,
                                                    const float* __restrict__ pos1,
                                                    const unsigned short* __restrict__ pack,
                                                    const float* __restrict__ qT,
                                                    const float* __restrict__ kT,
                                                    const float* __restrict__ vT,
                                                    const int* __restrict__ nn,
                                                    float* __restrict__ out) {
    __shared__ __align__(16) unsigned short XbT[NCOL * 64];   // pe1^T then X^T, swizzled
    __shared__ __align__(16) unsigned short HqT[NCOL * 64];   // H-quarter^T, swizzled
    __shared__ float relb[KNN][3];
    __shared__ float ab[108];
    __shared__ float gbuf[3][NCOL];
    __shared__ int nidx[KNN];

    const int n = blockIdx.x, t = threadIdx.x;
    const int lane = t & 63, wave = t >> 6;
    const int c16 = lane & 15, g = lane >> 4;
    const int mw = wave & 3;
    const int nw = wave >> 2;

    if (t < 108) ab[t] = anchors[t];
    if (t < KNN) {
        int m = nn[n * KNN + t];
        nidx[t] = m;
        relb[t][0] = xyz[n] - xyz[m];
        relb[t][1] = xyz[NPTS + n] - xyz[NPTS + m];
        relb[t][2] = xyz[2 * NPTS + n] - xyz[2 * NPTS + m];
    }
    __syncthreads();

    // ---- step 0: G[row][col] = (A_a @ rel_k)[row] ----
    for (int e = t; e < 3 * NCOL; e += 512) {
        int row = e / NCOL, col = e % NCOL;
        int a = col >> 4, k = col & 15;
        gbuf[row][col] = ab[a * 9 + row * 3 + 0] * relb[k][0]
                       + ab[a * 9 + row * 3 + 1] * relb[k][1]
                       + ab[a * 9 + row * 3 + 2] * relb[k][2];
    }
    __syncthreads();

    // ---- step 1: pe1^T = relu(P1 @ G)^T -> XbT ----
    {
        const float p10 = pos1[lane * 3 + 0], p11 = pos1[lane * 3 + 1], p12 = pos1[lane * 3 + 2];
        #pragma unroll
        for (int j = 0; j < 24; ++j) {
            int row = wave + 8 * j;
            float p = p10 * gbuf[0][row] + p11 * gbuf[1][row] + p12 * gbuf[2][row];
            XbT[swz(row, lane)] = f2bfu(p > 0.f ? p : 0.f);
        }
    }
    __syncthreads();

    const bf16x8* pk16 = (const bf16x8*)pack;
    const f32x4 zero4 = {0.f, 0.f, 0.f, 0.f};

    // ---- phase 0: pe^T = pe1^T @ P2^T ----
    f32x4 peacc[6] = {zero4, zero4, zero4, zero4, zero4, zero4};
    #pragma unroll
    for (int kt = 0; kt < 2; ++kt) {
        bf16x8 b0 = pk16[((2 * nw + 0) * 2 + kt) * 64 + lane];
        bf16x8 b1 = pk16[((2 * nw + 1) * 2 + kt) * 64 + lane];
        #pragma unroll
        for (int mi = 0; mi < 3; ++mi) {
            bf16x8 af = *(const bf16x8*)&XbT[swz((mw + 4 * mi) * 16 + c16, kt * 32 + g * 8)];
            peacc[mi * 2 + 0] = __builtin_amdgcn_mfma_f32_16x16x32_bf16(af, b0, peacc[mi * 2 + 0], 0, 0, 0);
            peacc[mi * 2 + 1] = __builtin_amdgcn_mfma_f32_16x16x32_bf16(af, b1, peacc[mi * 2 + 1], 0, 0, 0);
        }
    }

    // ---- step 3: X = q - k_g + pe (regs), vg = v_g + pe (stays in regs) ----
    float vgk[6][4], xreg[6][4];
    {
        const int m0 = nidx[4 * g + 0], m1 = nidx[4 * g + 1];
        const int m2 = nidx[4 * g + 2], m3 = nidx[4 * g + 3];
        #pragma unroll
        for (int mi = 0; mi < 3; ++mi) {
            int a = mw + 4 * mi;
            #pragma unroll
            for (int ni = 0; ni < 2; ++ni) {
                int tile = mi * 2 + ni;
                int d = (2 * nw + ni) * 16 + c16;
                float qv = qT[(n * NA + a) * DIM + d];
                int b0 = (m0 * NA + a) * DIM + d, b1 = (m1 * NA + a) * DIM + d;
                int b2 = (m2 * NA + a) * DIM + d, b3 = (m3 * NA + a) * DIM + d;
                xreg[tile][0] = qv - kT[b0] + peacc[tile][0]; vgk[tile][0] = vT[b0] + peacc[tile][0];
                xreg[tile][1] = qv - kT[b1] + peacc[tile][1]; vgk[tile][1] = vT[b1] + peacc[tile][1];
                xreg[tile][2] = qv - kT[b2] + peacc[tile][2]; vgk[tile][2] = vT[b2] + peacc[tile][2];
                xreg[tile][3] = qv - kT[b3] + peacc[tile][3]; vgk[tile][3] = vT[b3] + peacc[tile][3];
            }
        }
    }
    __syncthreads();   // phase-0 XbT reads complete before overwrite
    #pragma unroll
    for (int mi = 0; mi < 3; ++mi)
        #pragma unroll
        for (int ni = 0; ni < 2; ++ni) {
            int tile = mi * 2 + ni;
            int col = (2 * nw + ni) * 16 + c16;
            #pragma unroll
            for (int r = 0; r < 4; ++r)
                XbT[swz((mw + 4 * mi) * 16 + 4 * g + r, col)] = f2bfu(xreg[tile][r]);
        }
    __syncthreads();

    // ---- 4 rounds: Hq^T = relu(X^T @ W1q^T); S^T += Hq^T @ W2q^T ----
    f32x4 sacc[6] = {zero4, zero4, zero4, zero4, zero4, zero4};
    for (int hq = 0; hq < 4; ++hq) {
        f32x4 hacc[6] = {zero4, zero4, zero4, zero4, zero4, zero4};
        #pragma unroll
        for (int kt = 0; kt < 2; ++kt) {
            bf16x8 b0 = pk16[(8 + (hq * 4 + 2 * nw + 0) * 2 + kt) * 64 + lane];
            bf16x8 b1 = pk16[(8 + (hq * 4 + 2 * nw + 1) * 2 + kt) * 64 + lane];
            #pragma unroll
            for (int mi = 0; mi < 3; ++mi) {
                bf16x8 af = *(const bf16x8*)&XbT[swz((mw + 4 * mi) * 16 + c16, kt * 32 + g * 8)];
                hacc[mi * 2 + 0] = __builtin_amdgcn_mfma_f32_16x16x32_bf16(af, b0, hacc[mi * 2 + 0], 0, 0, 0);
                hacc[mi * 2 + 1] = __builtin_amdgcn_mfma_f32_16x16x32_bf16(af, b1, hacc[mi * 2 + 1], 0, 0, 0);
            }
        }
        #pragma unroll
        for (int mi = 0; mi < 3; ++mi)
            #pragma unroll
            for (int ni = 0; ni < 2; ++ni) {
                int tile = mi * 2 + ni;
                int col = (2 * nw + ni) * 16 + c16;
                #pragma unroll
                for (int r = 0; r < 4; ++r)
                    HqT[swz((mw + 4 * mi) * 16 + 4 * g + r, col)] = f2bfu(fmaxf(hacc[tile][r], 0.f));
            }
        __syncthreads();
        #pragma unroll
        for (int kt = 0; kt < 2; ++kt) {
            bf16x8 b0 = pk16[(40 + hq * 8 + (2 * nw + 0) * 2 + kt) * 64 + lane];
            bf16x8 b1 = pk16[(40 + hq * 8 + (2 * nw + 1) * 2 + kt) * 64 + lane];
            #pragma unroll
            for (int mi = 0; mi < 3; ++mi) {
                bf16x8 af = *(const bf16x8*)&HqT[swz((mw + 4 * mi) * 16 + c16, kt * 32 + g * 8)];
                sacc[mi * 2 + 0] = __builtin_amdgcn_mfma_f32_16x16x32_bf16(af, b0, sacc[mi * 2 + 0], 0, 0, 0);
                sacc[mi * 2 + 1] = __builtin_amdgcn_mfma_f32_16x16x32_bf16(af, b1, sacc[mi * 2 + 1], 0, 0, 0);
            }
        }
        __syncthreads();
    }

    // ---- epilogue: softmax over k = (4g+r); reg-sum over r, 2 shuffles over g ----
    #pragma unroll
    for (int mi = 0; mi < 3; ++mi) {
        int a = mw + 4 * mi;
        #pragma unroll
        for (int ni = 0; ni < 2; ++ni) {
            int tile = mi * 2 + ni;
            int d = (2 * nw + ni) * 16 + c16;
            float e0 = __expf(sacc[tile][0]);
            float e1 = __expf(sacc[tile][1]);
            float e2 = __expf(sacc[tile][2]);
            float e3 = __expf(sacc[tile][3]);
            float den = (e0 + e1) + (e2 + e3);
            float num = (e0 * vgk[tile][0] + e1 * vgk[tile][1]) + (e2 * vgk[tile][2] + e3 * vgk[tile][3]);
            den += __shfl_xor(den, 16); num += __shfl_xor(num, 16);
            den += __shfl_xor(den, 32); num += __shfl_xor(num, 32);
            if (g == 0)
                out[(d * NPTS + n) * NA + a] = num / den;
        }
    }
}

extern "C" void kernel_launch(void* const* d_in, const int* in_sizes, int n_in,
                              void* d_out, int out_size, void* d_ws, size_t ws_size,
                              hipStream_t stream) {
    const float* xyz     = (const float*)d_in[0];
    const float* feats   = (const float*)d_in[1];
    const float* anchors = (const float*)d_in[2];
    const float* to_qkv  = (const float*)d_in[3];
    const float* pos1    = (const float*)d_in[4];
    const float* pos2    = (const float*)d_in[5];
    const float* am1     = (const float*)d_in[6];
    const float* am2     = (const float*)d_in[7];
    float* out = (float*)d_out;

    float* ws = (float*)d_ws;
    const int seg = NPTS * NA * DIM;
    float* qT = ws;
    float* kT = ws + seg;
    float* vT = ws + 2 * seg;
    int* nn = (int*)(ws + 3 * seg);
    unsigned short* pack = (unsigned short*)(ws + 3 * seg + NPTS * KNN);

    prep_kernel<<<768, 256, 0, stream>>>(feats, to_qkv, qT, pack, pos2, am1, am2, xyz, nn);
    attn_main<<<NPTS, 512, 0, stream>>>(xyz, anchors, pos1, pack, qT, kT, vT, nn, out);
}

// Round 8
// 91.503 us; speedup vs baseline: 1.5491x; 1.5491x over previous
//
#include <hip/hip_runtime.h>

#define NPTS 1024
#define DIM 64
#define KNN 16
#define NA 12
#define NCOL 192              // (a,k) rows, idx = a*16 + k

typedef __attribute__((ext_vector_type(8))) short bf16x8;
typedef __attribute__((ext_vector_type(4))) float f32x4;

static __device__ inline unsigned short f2bfu(float x) {
    __bf16 b = (__bf16)x;                       // hw v_cvt (RNE)
    return __builtin_bit_cast(unsigned short, b);
}
static __device__ inline float bf2f(unsigned short s) {
    return __uint_as_float(((unsigned)s) << 16);
}
static __device__ inline unsigned pk2(float lo, float hi) {
    return (unsigned)f2bfu(lo) | ((unsigned)f2bfu(hi) << 16);
}
static __device__ inline bf16x8 load8_cvt(const float* p) {
    f32x4 u = *(const f32x4*)p;
    f32x4 v = *(const f32x4*)(p + 4);
    bf16x8 r;
    r[0] = (short)f2bfu(u[0]); r[1] = (short)f2bfu(u[1]); r[2] = (short)f2bfu(u[2]); r[3] = (short)f2bfu(u[3]);
    r[4] = (short)f2bfu(v[0]); r[5] = (short)f2bfu(v[1]); r[6] = (short)f2bfu(v[2]); r[7] = (short)f2bfu(v[3]);
    return r;
}

// T2-style XOR swizzle on a [192][64] u16 tile: xor the 16B-slot index (col bits 3-5)
// with row&7. Bijective per row; keeps 16B alignment for b128 frag reads.
static __device__ inline int swz(int row, int col) {
    return (row << 6) + (col ^ ((row & 7) << 3));
}

// ---------------- prep kernel: 768 blocks x 256 thr (unchanged) ----------------
__global__ __launch_bounds__(256) void prep_kernel(const float* __restrict__ feats,
                                                   const float* __restrict__ to_qkv,
                                                   float* __restrict__ qkvT,
                                                   unsigned short* __restrict__ pack,
                                                   const float* __restrict__ pos2,
                                                   const float* __restrict__ am1,
                                                   const float* __restrict__ am2,
                                                   const float* __restrict__ xyz,
                                                   int* __restrict__ idxout) {
    __shared__ unsigned short XT[16][72];
    __shared__ float px[NPTS], py[NPTS], pz[NPTS];
    const int b = blockIdx.x;
    const int t = threadIdx.x;
    const int n0 = b * 16;
    const bool do_knn = (b < 256);

    if (b < 72 && t < 64) {
        int s = b;
        int c16p = t & 15, gp = t >> 4;
        const float* src;
        if (s < 8) {
            int nt = s >> 1, kt = s & 1;
            src = pos2 + (nt * 16 + c16p) * 64 + kt * 32 + gp * 8;
        } else if (s < 40) {
            int u = s - 8, hq = u >> 3, nt = (u >> 1) & 3, kt = u & 1;
            src = am1 + (hq * 64 + nt * 16 + c16p) * 64 + kt * 32 + gp * 8;
        } else {
            int u = s - 40, hq = u >> 3, nt = (u >> 1) & 3, kt = u & 1;
            src = am2 + (nt * 16 + c16p) * 256 + hq * 64 + kt * 32 + gp * 8;
        }
        unsigned short* dst = pack + (s * 64 + t) * 8;
        #pragma unroll
        for (int e = 0; e < 8; ++e) dst[e] = f2bfu(src[e]);
    }

    if (do_knn) {
        for (int m = t; m < NPTS; m += 256) {
            px[m] = xyz[m];
            py[m] = xyz[NPTS + m];
            pz[m] = xyz[2 * NPTS + m];
        }
    }
    for (int e = t; e < 16 * 64; e += 256) {
        int c = e & 15, i = e >> 4;
        XT[c][i] = f2bfu(feats[i * (NPTS * NA) + n0 + c]);
    }
    __syncthreads();

    const int lane = t & 63, w = t >> 6, c16 = lane & 15, g = lane >> 4;

    {
        const f32x4 zero4 = {0.f, 0.f, 0.f, 0.f};
        f32x4 acc[3] = {zero4, zero4, zero4};
        #pragma unroll
        for (int kt = 0; kt < 2; ++kt) {
            bf16x8 af = *(const bf16x8*)&XT[c16][kt * 32 + g * 8];
            #pragma unroll
            for (int ni = 0; ni < 3; ++ni) {
                int cd = (w * 3 + ni) * 16 + c16;
                bf16x8 bfr = load8_cvt(to_qkv + cd * 64 + kt * 32 + g * 8);
                acc[ni] = __builtin_amdgcn_mfma_f32_16x16x32_bf16(af, bfr, acc[ni], 0, 0, 0);
            }
        }
        #pragma unroll
        for (int ni = 0; ni < 3; ++ni) {
            int cd = (w * 3 + ni) * 16 + c16;
            int c = cd >> 6, d = cd & 63;
            #pragma unroll
            for (int r = 0; r < 4; ++r) {
                int na = n0 + 4 * g + r;
                qkvT[c * (NPTS * NA * DIM) + na * 64 + d] = acc[ni][r];
            }
        }
    }

    if (do_knn) {
        const int n = b * 4 + w;
        const float xn = px[n], yn = py[n], zn = pz[n];
        const float sqn = xn * xn + yn * yn + zn * zn;
        float dd[16]; int id[16];
        #pragma unroll
        for (int j = 0; j < 16; ++j) {
            int m = j * 64 + lane;
            float xm = px[m], ym = py[m], zm = pz[m];
            float sqm = xm * xm + ym * ym + zm * zm;
            float dot = xn * xm + yn * ym + zn * zm;
            dd[j] = sqn + sqm - 2.f * dot;
            id[j] = m;
        }
        for (int r = 0; r < KNN; ++r) {
            float bd = 1e30f; int bi = 0x7fffffff;
            #pragma unroll
            for (int j = 0; j < 16; ++j)
                if (dd[j] < bd || (dd[j] == bd && id[j] < bi)) { bd = dd[j]; bi = id[j]; }
            #pragma unroll
            for (int mask = 1; mask < 64; mask <<= 1) {
                float od = __shfl_xor(bd, mask);
                int oi = __shfl_xor(bi, mask);
                if (od < bd || (od == bd && oi < bi)) { bd = od; bi = oi; }
            }
            if (lane == 0) idxout[n * KNN + r] = bi;
            #pragma unroll
            for (int j = 0; j < 16; ++j)
                if (id[j] == bi) dd[j] = 1e30f;
        }
    }
}

// ---------------- attn kernel: swizzled 52KB LDS + launch_bounds(512,4), bf16-packed vg ----------------
// 8 waves: mw = wave&3 -> m-tiles {mw, mw+4, mw+8}; nw = wave>>2 -> n-tiles {2nw, 2nw+1}.
// C layout: lane(c16,g) reg r holds D[(a=mt, k=4g+r)][out = nt*16+c16].
__global__ __launch_bounds__(512, 4) void attn_main(const float* __restrict__ xyz,
                                                    const float* __restrict__ anchors,
                                                    const float* __restrict__ pos1,
                                                    const unsigned short* __restrict__ pack,
                                                    const float* __restrict__ qT,
                                                    const float* __restrict__ kT,
                                                    const float* __restrict__ vT,
                                                    const int* __restrict__ nn,
                                                    float* __restrict__ out) {
    __shared__ __align__(16) unsigned short XbT[NCOL * 64];   // pe1^T then X^T, swizzled
    __shared__ __align__(16) unsigned short HqT[NCOL * 64];   // H-quarter^T, swizzled
    __shared__ float relb[KNN][3];
    __shared__ float ab[108];
    __shared__ float gbuf[3][NCOL];
    __shared__ int nidx[KNN];

    const int n = blockIdx.x, t = threadIdx.x;
    const int lane = t & 63, wave = t >> 6;
    const int c16 = lane & 15, g = lane >> 4;
    const int mw = wave & 3;
    const int nw = wave >> 2;

    if (t < 108) ab[t] = anchors[t];
    if (t < KNN) {
        int m = nn[n * KNN + t];
        nidx[t] = m;
        relb[t][0] = xyz[n] - xyz[m];
        relb[t][1] = xyz[NPTS + n] - xyz[NPTS + m];
        relb[t][2] = xyz[2 * NPTS + n] - xyz[2 * NPTS + m];
    }
    __syncthreads();

    // ---- step 0: G[row][col] = (A_a @ rel_k)[row] ----
    for (int e = t; e < 3 * NCOL; e += 512) {
        int row = e / NCOL, col = e % NCOL;
        int a = col >> 4, k = col & 15;
        gbuf[row][col] = ab[a * 9 + row * 3 + 0] * relb[k][0]
                       + ab[a * 9 + row * 3 + 1] * relb[k][1]
                       + ab[a * 9 + row * 3 + 2] * relb[k][2];
    }
    __syncthreads();

    // ---- step 1: pe1^T = relu(P1 @ G)^T -> XbT ----
    {
        const float p10 = pos1[lane * 3 + 0], p11 = pos1[lane * 3 + 1], p12 = pos1[lane * 3 + 2];
        #pragma unroll
        for (int j = 0; j < 24; ++j) {
            int row = wave + 8 * j;
            float p = p10 * gbuf[0][row] + p11 * gbuf[1][row] + p12 * gbuf[2][row];
            XbT[swz(row, lane)] = f2bfu(p > 0.f ? p : 0.f);
        }
    }
    __syncthreads();

    const bf16x8* pk16 = (const bf16x8*)pack;
    const f32x4 zero4 = {0.f, 0.f, 0.f, 0.f};

    // ---- phase 0: pe^T = pe1^T @ P2^T ----
    f32x4 peacc[6] = {zero4, zero4, zero4, zero4, zero4, zero4};
    #pragma unroll
    for (int kt = 0; kt < 2; ++kt) {
        bf16x8 b0 = pk16[((2 * nw + 0) * 2 + kt) * 64 + lane];
        bf16x8 b1 = pk16[((2 * nw + 1) * 2 + kt) * 64 + lane];
        #pragma unroll
        for (int mi = 0; mi < 3; ++mi) {
            bf16x8 af = *(const bf16x8*)&XbT[swz((mw + 4 * mi) * 16 + c16, kt * 32 + g * 8)];
            peacc[mi * 2 + 0] = __builtin_amdgcn_mfma_f32_16x16x32_bf16(af, b0, peacc[mi * 2 + 0], 0, 0, 0);
            peacc[mi * 2 + 1] = __builtin_amdgcn_mfma_f32_16x16x32_bf16(af, b1, peacc[mi * 2 + 1], 0, 0, 0);
        }
    }

    // ---- step 3: X = q - k_g + pe (regs), vg = v_g + pe (bf16-packed regs) ----
    unsigned vgp[6][2];
    float xreg[6][4];
    {
        const int m0 = nidx[4 * g + 0], m1 = nidx[4 * g + 1];
        const int m2 = nidx[4 * g + 2], m3 = nidx[4 * g + 3];
        #pragma unroll
        for (int mi = 0; mi < 3; ++mi) {
            int a = mw + 4 * mi;
            #pragma unroll
            for (int ni = 0; ni < 2; ++ni) {
                int tile = mi * 2 + ni;
                int d = (2 * nw + ni) * 16 + c16;
                float qv = qT[(n * NA + a) * DIM + d];
                int b0 = (m0 * NA + a) * DIM + d, b1 = (m1 * NA + a) * DIM + d;
                int b2 = (m2 * NA + a) * DIM + d, b3 = (m3 * NA + a) * DIM + d;
                float vg0 = vT[b0] + peacc[tile][0], vg1 = vT[b1] + peacc[tile][1];
                float vg2 = vT[b2] + peacc[tile][2], vg3 = vT[b3] + peacc[tile][3];
                xreg[tile][0] = qv - kT[b0] + peacc[tile][0];
                xreg[tile][1] = qv - kT[b1] + peacc[tile][1];
                xreg[tile][2] = qv - kT[b2] + peacc[tile][2];
                xreg[tile][3] = qv - kT[b3] + peacc[tile][3];
                vgp[tile][0] = pk2(vg0, vg1);
                vgp[tile][1] = pk2(vg2, vg3);
            }
        }
    }
    __syncthreads();   // phase-0 XbT reads complete before overwrite
    #pragma unroll
    for (int mi = 0; mi < 3; ++mi)
        #pragma unroll
        for (int ni = 0; ni < 2; ++ni) {
            int tile = mi * 2 + ni;
            int col = (2 * nw + ni) * 16 + c16;
            #pragma unroll
            for (int r = 0; r < 4; ++r)
                XbT[swz((mw + 4 * mi) * 16 + 4 * g + r, col)] = f2bfu(xreg[tile][r]);
        }
    __syncthreads();

    // ---- 4 rounds: Hq^T = relu(X^T @ W1q^T); S^T += Hq^T @ W2q^T ----
    f32x4 sacc[6] = {zero4, zero4, zero4, zero4, zero4, zero4};
    for (int hq = 0; hq < 4; ++hq) {
        f32x4 hacc[6] = {zero4, zero4, zero4, zero4, zero4, zero4};
        #pragma unroll
        for (int kt = 0; kt < 2; ++kt) {
            bf16x8 b0 = pk16[(8 + (hq * 4 + 2 * nw + 0) * 2 + kt) * 64 + lane];
            bf16x8 b1 = pk16[(8 + (hq * 4 + 2 * nw + 1) * 2 + kt) * 64 + lane];
            #pragma unroll
            for (int mi = 0; mi < 3; ++mi) {
                bf16x8 af = *(const bf16x8*)&XbT[swz((mw + 4 * mi) * 16 + c16, kt * 32 + g * 8)];
                hacc[mi * 2 + 0] = __builtin_amdgcn_mfma_f32_16x16x32_bf16(af, b0, hacc[mi * 2 + 0], 0, 0, 0);
                hacc[mi * 2 + 1] = __builtin_amdgcn_mfma_f32_16x16x32_bf16(af, b1, hacc[mi * 2 + 1], 0, 0, 0);
            }
        }
        #pragma unroll
        for (int mi = 0; mi < 3; ++mi)
            #pragma unroll
            for (int ni = 0; ni < 2; ++ni) {
                int tile = mi * 2 + ni;
                int col = (2 * nw + ni) * 16 + c16;
                #pragma unroll
                for (int r = 0; r < 4; ++r)
                    HqT[swz((mw + 4 * mi) * 16 + 4 * g + r, col)] = f2bfu(fmaxf(hacc[tile][r], 0.f));
            }
        __syncthreads();
        #pragma unroll
        for (int kt = 0; kt < 2; ++kt) {
            bf16x8 b0 = pk16[(40 + hq * 8 + (2 * nw + 0) * 2 + kt) * 64 + lane];
            bf16x8 b1 = pk16[(40 + hq * 8 + (2 * nw + 1) * 2 + kt) * 64 + lane];
            #pragma unroll
            for (int mi = 0; mi < 3; ++mi) {
                bf16x8 af = *(const bf16x8*)&HqT[swz((mw + 4 * mi) * 16 + c16, kt * 32 + g * 8)];
                sacc[mi * 2 + 0] = __builtin_amdgcn_mfma_f32_16x16x32_bf16(af, b0, sacc[mi * 2 + 0], 0, 0, 0);
                sacc[mi * 2 + 1] = __builtin_amdgcn_mfma_f32_16x16x32_bf16(af, b1, sacc[mi * 2 + 1], 0, 0, 0);
            }
        }
        __syncthreads();
    }

    // ---- epilogue: softmax over k = (4g+r); reg-sum over r, 2 shuffles over g ----
    #pragma unroll
    for (int mi = 0; mi < 3; ++mi) {
        int a = mw + 4 * mi;
        #pragma unroll
        for (int ni = 0; ni < 2; ++ni) {
            int tile = mi * 2 + ni;
            int d = (2 * nw + ni) * 16 + c16;
            float e0 = __expf(sacc[tile][0]);
            float e1 = __expf(sacc[tile][1]);
            float e2 = __expf(sacc[tile][2]);
            float e3 = __expf(sacc[tile][3]);
            float den = (e0 + e1) + (e2 + e3);
            unsigned v01 = vgp[tile][0], v23 = vgp[tile][1];
            float num = (e0 * bf2f((unsigned short)(v01 & 0xffff)) + e1 * bf2f((unsigned short)(v01 >> 16)))
                      + (e2 * bf2f((unsigned short)(v23 & 0xffff)) + e3 * bf2f((unsigned short)(v23 >> 16)));
            den += __shfl_xor(den, 16); num += __shfl_xor(num, 16);
            den += __shfl_xor(den, 32); num += __shfl_xor(num, 32);
            if (g == 0)
                out[(d * NPTS + n) * NA + a] = num / den;
        }
    }
}

extern "C" void kernel_launch(void* const* d_in, const int* in_sizes, int n_in,
                              void* d_out, int out_size, void* d_ws, size_t ws_size,
                              hipStream_t stream) {
    const float* xyz     = (const float*)d_in[0];
    const float* feats   = (const float*)d_in[1];
    const float* anchors = (const float*)d_in[2];
    const float* to_qkv  = (const float*)d_in[3];
    const float* pos1    = (const float*)d_in[4];
    const float* pos2    = (const float*)d_in[5];
    const float* am1     = (const float*)d_in[6];
    const float* am2     = (const float*)d_in[7];
    float* out = (float*)d_out;

    float* ws = (float*)d_ws;
    const int seg = NPTS * NA * DIM;
    float* qT = ws;
    float* kT = ws + seg;
    float* vT = ws + 2 * seg;
    int* nn = (int*)(ws + 3 * seg);
    unsigned short* pack = (unsigned short*)(ws + 3 * seg + NPTS * KNN);

    prep_kernel<<<768, 256, 0, stream>>>(feats, to_qkv, qT, pack, pos2, am1, am2, xyz, nn);
    attn_main<<<NPTS, 512, 0, stream>>>(xyz, anchors, pos1, pack, qT, kT, vT, nn, out);
}